// Round 6
// baseline (672.069 us; speedup 1.0000x reference)
//
#include <hip/hip_runtime.h>

#define N_ROWS 32768
#define DIM    256
#define NE     256
#define KP     4096
#define NQ     4
#define ND     8388608   // N_ROWS*DIM
#define RESCORE_MARGIN 2e-4f

typedef short short8 __attribute__((ext_vector_type(8)));
typedef unsigned short ushort8v __attribute__((ext_vector_type(8)));
typedef float f32x4  __attribute__((ext_vector_type(4)));
typedef float f32x16 __attribute__((ext_vector_type(16)));

__device__ inline float bf2f(unsigned short u) {
  return __uint_as_float(((unsigned)u) << 16);
}
__device__ inline unsigned short f2bf(float f) {
  unsigned u = __float_as_uint(f);
  u += 0x7fffu + ((u >> 16) & 1u);
  return (unsigned short)(u >> 16);
}

// Fragment-major packed layout (16B chunks): chunk (tile*8+f)*64 + quad*16 + l16
// holds row tile*16+l16, dims [f*32+quad*8, +8). For row r, dim chunk j (=k/8):
// index ((r>>4)*8 + (j>>2))*64 + ((j&3)<<4) + (r&15).
// The 16B chunk is the atomic unit: both 16x16x32 fragments (row=l&15,
// j=f*4+(l>>4)) and 32x32x16 fragments (row=l&31, j=2f+(l>>5)) gather from
// this same array via different lane->chunk mappings.
__device__ inline size_t chunkIdx(int row, int j) {
  return (size_t)(((row >> 4) * 8 + (j >> 2)) * 64 + ((j & 3) << 4) + (row & 15));
}

// ---------------- stage 0 prep: packed Xn/rH/rL, rnorm (NO resid copy:
// x_q = x - resid_final identity lets stage 0 read x directly) ----------------
__global__ __launch_bounds__(256) void prep0_kernel(
    const float* __restrict__ x,
    unsigned short* __restrict__ Xnp, float* __restrict__ rnorm,
    unsigned short* __restrict__ rHp, unsigned short* __restrict__ rLp) {
  const int tid = threadIdx.x, wave = tid >> 6, lane = tid & 63;
  const int half = lane >> 5, j = lane & 31;
  const int row = blockIdx.x * 8 + wave * 2 + half;  // grid 4096
  const float4* xr = (const float4*)(x + (size_t)row * DIM + j * 8);
  float4 v0 = xr[0], v1 = xr[1];
  float vv[8] = {v0.x, v0.y, v0.z, v0.w, v1.x, v1.y, v1.z, v1.w};
  float ss = 0.f;
#pragma unroll
  for (int i = 0; i < 8; ++i) ss += vv[i] * vv[i];
#pragma unroll
  for (int m = 1; m < 32; m <<= 1) ss += __shfl_xor(ss, m, 64);
  if (j == 0) rnorm[row] = ss;
  const float sc = rsqrtf(ss + 1e-12f);
  ushort8v h, l, xn;
#pragma unroll
  for (int i = 0; i < 8; ++i) {
    h[i] = f2bf(vv[i]); l[i] = f2bf(vv[i] - bf2f(h[i])); xn[i] = f2bf(vv[i] * sc);
  }
  const size_t c = chunkIdx(row, j) * 8;
  *(ushort8v*)(rHp + c) = h;
  *(ushort8v*)(rLp + c) = l;
  *(ushort8v*)(Xnp + c) = xn;
}

// ---------------- all codebook row norms (NQ*NE rows), once ----------------
__global__ __launch_bounds__(256) void cbnorm_kernel(
    const float* __restrict__ cb, float* __restrict__ cbn) {
  const int wave = threadIdx.x >> 6, lane = threadIdx.x & 63;
  const int e = blockIdx.x * 4 + wave;  // 0..NQ*NE-1
  float4 v = ((const float4*)(cb + (size_t)e * DIM))[lane];
  float ss = v.x * v.x + v.y * v.y + v.z * v.z + v.w * v.w;
#pragma unroll
  for (int m = 1; m < 64; m <<= 1) ss += __shfl_xor(ss, m, 64);
  if (lane == 0) cbn[e] = ss;
}

// ---------------- codebook hi/lo split, packed, all stages, once ----------------
__global__ __launch_bounds__(256) void cbsplit_kernel(
    const float* __restrict__ cb, unsigned short* __restrict__ cbHp,
    unsigned short* __restrict__ cbLp) {
  const int p = blockIdx.x * 256 + threadIdx.x;  // grid 128 -> 32768 chunks
  const int stage = p >> 13, ps = p & 8191;
  const int l16 = ps & 15, quad = (ps >> 4) & 3, kf = (ps >> 6) & 7, et = ps >> 9;
  const int e = et * 16 + l16, k0 = kf * 32 + quad * 8;
  const float* src = cb + ((size_t)(stage * NE + e)) * DIM + k0;
  float4 v0 = ((const float4*)src)[0], v1 = ((const float4*)src)[1];
  float vv[8] = {v0.x, v0.y, v0.z, v0.w, v1.x, v1.y, v1.z, v1.w};
  ushort8v h, l;
#pragma unroll
  for (int i = 0; i < 8; ++i) {
    h[i] = f2bf(vv[i]); l[i] = f2bf(vv[i] - bf2f(h[i]));
  }
  *(ushort8v*)(cbHp + (size_t)p * 8) = h;
  *(ushort8v*)(cbLp + (size_t)p * 8) = l;
}

// ---------------- per-stage: gather xn[i1] (packed Qg) + pos; zero ssum ----------------
__global__ __launch_bounds__(256) void gather_pos_kernel(
    const unsigned short* __restrict__ Xnp, const int* __restrict__ i1,
    const int* __restrict__ i2, unsigned short* __restrict__ Qgp,
    float* __restrict__ pos, float* __restrict__ ssum) {
  if (blockIdx.x < 16) ssum[blockIdx.x * 256 + threadIdx.x] = 0.0f;
  const int wave = threadIdx.x >> 6, lane = threadIdx.x & 63;
  const int k = blockIdx.x * 4 + wave;
  const int a = i1[k], b = i2[k];
  const int j2 = lane >> 1, off = (lane & 1) * 4;
  ushort4 va = *(const ushort4*)(Xnp + chunkIdx(a, j2) * 8 + off);
  ushort4 vb = *(const ushort4*)(Xnp + chunkIdx(b, j2) * 8 + off);
  *(ushort4*)(Qgp + chunkIdx(k, j2) * 8 + off) = va;
  float d = bf2f(va.x) * bf2f(vb.x) + bf2f(va.y) * bf2f(vb.y) +
            bf2f(va.z) * bf2f(vb.z) + bf2f(va.w) * bf2f(vb.w);
#pragma unroll
  for (int m = 1; m < 64; m <<= 1) d += __shfl_xor(d, m, 64);
  if (lane == 0) pos[k] = d * 10.0f;  // /TEMP
}

// ---------------- per-stage: sim GEMM (MFMA) + sum(exp(logit-10)) ----------------
// v6: 32x32x16 MFMA + 32-row B groups + 1-barrier double-buffer.
// Budget math (per-SIMD units): old 16x16x32 structure = 33us MFMA pipe +
// 12us VALU + ~35us barrier/drain stall (64 barriers + lgkmcnt(0) drains).
// Now: MFMA pipe 27us (2382 TF shape), VALU ~8us (16 fma+exp+add per 1024
// logits, zero-C const kills per-tile zero-movs), 16 barriers (dbuf needs no
// read-drain barrier: reads of buf[pp] vs stage writes to buf[pp^1] disjoint).
// Per iter: vmcnt(0) [own stage landed; issued a full iter ago -> cheap] ->
// barrier -> stage(g+1) -> 16 ds_read + 16 MFMA (2 split-K chains) + epilogue.
// A-fragments (row=l&31, k=(l>>5)*8+j) gather from the SAME packed Qgp via
// per-lane addressing: tile*4096 + h*128 + (l&15)*8 + f*256 (ushorts).
// C layout (m74/m101): col=lane&31, row=(reg&3)+8*(reg>>2)+4*(lane>>5).
// NOTE: operand-resident design: NEVER >2 in launch_bounds min-waves (r1: a 4
// forced a 64-VGPR cap and spilled 1.5GB to scratch, 7x slower).
__global__ __launch_bounds__(256, 2) void sim_lse_kernel(
    const unsigned short* __restrict__ Qgp, const unsigned short* __restrict__ Xnp,
    float* __restrict__ s_sum) {
  __shared__ unsigned short ldsB[16384];  // 2 buffers x (32 rows x 256 bf16 = 16KB)
  const int tid  = threadIdx.x;
  const int lane = tid & 63;
  const int wave = tid >> 6;
  const int r32  = lane & 31;
  const int h    = lane >> 5;

  // XCD-aware bijective swizzle (hw round-robins flat id over 8 XCDs).
  const int fid = blockIdx.y * 32 + blockIdx.x;
  const int xcd = fid & 7;
  const int sl  = fid >> 3;
  const int bx  = sl & 31;              // q-tile group (128 q-rows)
  const int by  = xcd * 8 + (sl >> 5);  // n-chunk (512 n-rows), contiguous per XCD

  const int qbase = bx * 128 + wave * 32;

  // A: this wave's 32 q-rows, 16 K-fragments of 16 (f*256 ushort stride).
  const unsigned short* abase =
      Qgp + (size_t)(bx * 8 + wave * 2 + (r32 >> 4)) * 4096 + h * 128 + (r32 & 15) * 8;
  short8 a[16];
#pragma unroll
  for (int f = 0; f < 16; ++f) a[f] = *(const short8*)(abase + f * 256);

  float s[16];
#pragma unroll
  for (int i = 0; i < 16; ++i) s[i] = 0.f;
  const f32x16 z16 = {0.f, 0.f, 0.f, 0.f, 0.f, 0.f, 0.f, 0.f,
                      0.f, 0.f, 0.f, 0.f, 0.f, 0.f, 0.f, 0.f};
  const float C1 = 14.4269504088896341f;  // 10*log2(e); exp(10d-10)=exp2(d*C1-C1)

  // LDS read base (bytes) for B fragments: row=r32, k-chunk j=2f+h ->
  // byte = (r32>>4)*8192 + h*256 + (r32&15)*16 + f*512.
  const int lbase = (r32 >> 4) * 8192 + h * 256 + (r32 & 15) * 16;

  // Stage group g (32 rows = 2 packed tiles = 16KB contiguous) into buffer pp.
  // 4 waves x 4 x (64 lanes x 16B) linear copy; LDS dest = uniform base + lane*16.
  auto stageB = [&](int g, int pp) {
    const unsigned short* sp =
        Xnp + (size_t)(by * 32 + g * 2) * 4096 + wave * 512 + lane * 8;
    unsigned short* dp = &ldsB[pp * 8192 + wave * 512 + lane * 8];
#pragma unroll
    for (int p = 0; p < 4; ++p)
      __builtin_amdgcn_global_load_lds(
          (const __attribute__((address_space(1))) unsigned int*)(sp + p * 2048),
          (__attribute__((address_space(3))) unsigned int*)(dp + p * 2048),
          16, 0, 0);
  };

  stageB(0, 0);
  for (int g = 0; g < 16; ++g) {
    const int pp = g & 1;
    // own stage(g) loads landed (issued a full iteration ago), then sync:
    // all waves' stage(g) landed AND all waves done reading buf[pp^1].
    asm volatile("s_waitcnt vmcnt(0)" ::: "memory");
    __builtin_amdgcn_s_barrier();
    __builtin_amdgcn_sched_barrier(0);
    if (g + 1 < 16) stageB(g + 1, pp ^ 1);  // async into the other buffer

    const char* bufR = (const char*)&ldsB[pp * 8192];
    short8 b[16];
#pragma unroll
    for (int f = 0; f < 16; ++f)
      b[f] = *(const short8*)(bufR + lbase + f * 512);

    // 2 independent split-K chains (k 0..127 / 128..255), zero-const C start.
    f32x16 accA = __builtin_amdgcn_mfma_f32_32x32x16_bf16(a[0], b[0], z16, 0, 0, 0);
    f32x16 accB = __builtin_amdgcn_mfma_f32_32x32x16_bf16(a[8], b[8], z16, 0, 0, 0);
#pragma unroll
    for (int f = 1; f < 8; ++f) {
      accA = __builtin_amdgcn_mfma_f32_32x32x16_bf16(a[f], b[f], accA, 0, 0, 0);
      accB = __builtin_amdgcn_mfma_f32_32x32x16_bf16(a[f + 8], b[f + 8], accB, 0, 0, 0);
    }
#pragma unroll
    for (int i = 0; i < 16; ++i)
      s[i] += exp2f(fmaf(accA[i] + accB[i], C1, -C1));
  }

  // sum over 32 n-cols (lane&31); rows live per (reg, half-wave).
#pragma unroll
  for (int m = 1; m < 32; m <<= 1)
#pragma unroll
    for (int i = 0; i < 16; ++i) s[i] += __shfl_xor(s[i], m, 64);
  if (r32 == 0) {
#pragma unroll
    for (int i = 0; i < 16; ++i) {
      const int row = (i & 3) + 8 * (i >> 2) + 4 * h;
      atomicAdd(&s_sum[qbase + row], s[i]);
    }
  }
}

// ---------------- per-stage: lse -> outer loss accumulator ----------------
__global__ __launch_bounds__(256) void lse_final_kernel(
    const float* __restrict__ s_sum, const float* __restrict__ pos,
    float* __restrict__ acc, int stage) {
  const int t = threadIdx.x;
  const int k = blockIdx.x * 256 + t;
  float v = 10.0f + __logf(s_sum[k]) - pos[k];
#pragma unroll
  for (int m = 1; m < 64; m <<= 1) v += __shfl_xor(v, m, 64);
  __shared__ float red[4];
  if ((t & 63) == 0) red[t >> 6] = v;
  __syncthreads();
  if (t == 0) atomicAdd(&acc[4 + stage], red[0] + red[1] + red[2] + red[3]);
}

// ---------------- per-stage: MFMA argmin (hi/lo) + fp32 rescore + update ----------------
// 32 rows/block (grid 1024). Packed operands, kf-loop register ping-pong.
// Memory-traffic notes:
//  - stage 0 reads residual from x directly (no x->resid copy)
//  - xq is NOT accumulated: x_q = x - resid_final; stage 3 writes xq = x - nr.
__global__ __launch_bounds__(256, 2) void argmin_update_kernel(
    const float* __restrict__ xin, float* __restrict__ resid,
    const float* __restrict__ cb,
    const unsigned short* __restrict__ cbHp, const unsigned short* __restrict__ cbLp,
    const float* __restrict__ cbn, float* __restrict__ rnorm,
    unsigned short* rHp, unsigned short* rLp,
    float* __restrict__ xq, float* __restrict__ idxf, float* __restrict__ acc,
    unsigned short* __restrict__ Xnp, int stage) {
  __shared__ float sV1[4][32];
  __shared__ float sV2[4][32];
  __shared__ int   sIx[4][32];
  __shared__ int   sIdx[32];
  __shared__ int   sFlag[32];
  __shared__ float sred[4];
  const int tid  = threadIdx.x;
  const int lane = tid & 63;
  const int wave = tid >> 6;
  const int quad = lane >> 4;
  const int l16  = lane & 15;
  const int rbase = blockIdx.x * 32;
  const int t0 = blockIdx.x * 2;
  const float* __restrict__ src = (stage == 0) ? xin : resid;  // current residual

  f32x4 acc4[2][4];  // [rt][ct] : row rt*16+quad*4+i, e (wave*4+ct)*16+l16
#pragma unroll
  for (int rt = 0; rt < 2; ++rt)
#pragma unroll
    for (int ct = 0; ct < 4; ++ct) acc4[rt][ct] = (f32x4){0.f, 0.f, 0.f, 0.f};

  auto loadA = [&](int kf, short8 (&aH)[2], short8 (&aL)[2]) {
#pragma unroll
    for (int rt = 0; rt < 2; ++rt) {
      const size_t off = ((size_t)(((t0 + rt) * 8 + kf) * 64 + lane)) * 8;
      aH[rt] = *(const short8*)(rHp + off);
      aL[rt] = *(const short8*)(rLp + off);
    }
  };
  auto loadBc = [&](int kf, short8 (&bH)[4], short8 (&bL)[4]) {
#pragma unroll
    for (int ct = 0; ct < 4; ++ct) {
      const size_t boff = ((size_t)(((wave * 4 + ct) * 8 + kf) * 64 + lane)) * 8;
      bH[ct] = *(const short8*)(cbHp + boff);
      bL[ct] = *(const short8*)(cbLp + boff);
    }
  };
  auto computeK = [&](short8 (&aH)[2], short8 (&aL)[2], short8 (&bH)[4],
                      short8 (&bL)[4]) {
#pragma unroll
    for (int ct = 0; ct < 4; ++ct)
#pragma unroll
      for (int rt = 0; rt < 2; ++rt) {
        acc4[rt][ct] = __builtin_amdgcn_mfma_f32_16x16x32_bf16(aL[rt], bH[ct], acc4[rt][ct], 0, 0, 0);
        acc4[rt][ct] = __builtin_amdgcn_mfma_f32_16x16x32_bf16(aH[rt], bL[ct], acc4[rt][ct], 0, 0, 0);
        acc4[rt][ct] = __builtin_amdgcn_mfma_f32_16x16x32_bf16(aH[rt], bH[ct], acc4[rt][ct], 0, 0, 0);
      }
  };

  short8 aH0[2], aL0[2], bH0[4], bL0[4], aH1[2], aL1[2], bH1[4], bL1[4];
  loadA(0, aH0, aL0); loadBc(0, bH0, bL0);
  for (int kf = 0; kf < 8; kf += 2) {
    loadA(kf + 1, aH1, aL1); loadBc(kf + 1, bH1, bL1);
    computeK(aH0, aL0, bH0, bL0);
    if (kf + 2 < 8) { loadA(kf + 2, aH0, aL0); loadBc(kf + 2, bH0, bL0); }
    computeK(aH1, aL1, bH1, bL1);
  }

  // ---- epilogue: per-row top-2 over this wave's 64 e ----
  float cbe[4];
#pragma unroll
  for (int ct = 0; ct < 4; ++ct) cbe[ct] = cbn[(wave * 4 + ct) * 16 + l16];
#pragma unroll
  for (int rt = 0; rt < 2; ++rt) {
    float b1[4], b2[4]; int e1[4];
#pragma unroll
    for (int i = 0; i < 4; ++i) { b1[i] = 3.4e38f; b2[i] = 3.4e38f; e1[i] = 0; }
#pragma unroll
    for (int ct = 0; ct < 4; ++ct) {
      const int e = (wave * 4 + ct) * 16 + l16;
#pragma unroll
      for (int i = 0; i < 4; ++i) {
        const float v = fmaf(-2.0f, acc4[rt][ct][i], cbe[ct]);
        if (v < b1[i]) { b2[i] = b1[i]; b1[i] = v; e1[i] = e; }
        else if (v < b2[i]) b2[i] = v;
      }
    }
#pragma unroll
    for (int m = 1; m < 16; m <<= 1) {
#pragma unroll
      for (int i = 0; i < 4; ++i) {
        const float o1 = __shfl_xor(b1[i], m, 64);
        const float o2 = __shfl_xor(b2[i], m, 64);
        const int   oe = __shfl_xor(e1[i], m, 64);
        if (o1 < b1[i] || (o1 == b1[i] && oe < e1[i])) {
          b2[i] = fminf(b1[i], o2); b1[i] = o1; e1[i] = oe;
        } else {
          b2[i] = fminf(b2[i], o1);
        }
      }
    }
    if (l16 == 0) {
#pragma unroll
      for (int i = 0; i < 4; ++i) {
        const int r = rt * 16 + quad * 4 + i;
        sV1[wave][r] = b1[i]; sV2[wave][r] = b2[i]; sIx[wave][r] = e1[i];
      }
    }
  }
  __syncthreads();
  if (tid < 32) {
    float v1 = 3.4e38f, v2 = 3.4e38f; int ix = 0;
#pragma unroll
    for (int w = 0; w < 4; ++w) {
      const float a1 = sV1[w][tid], a2 = sV2[w][tid];
      const int ae = sIx[w][tid];
      if (a1 < v1) { v2 = fminf(v1, a2); v1 = a1; ix = ae; }
      else { v2 = fminf(v2, fminf(a1, a2)); }
    }
    sIdx[tid] = ix;
    sFlag[tid] = (v2 - v1 < RESCORE_MARGIN) ? 1 : 0;
  }
  __syncthreads();

  // ---- exact fp32 rescore for flagged rows (rare) ----
  for (int rr = 0; rr < 8; ++rr) {
    const int r = wave * 8 + rr;
    if (sFlag[r]) {
      const int row = rbase + r;
      const float* rrow = src + (size_t)row * DIM;
      float d[4] = {0.f, 0.f, 0.f, 0.f};
      for (int kb = 0; kb < 64; ++kb) {
        const float4 rv = ((const float4*)rrow)[kb];
#pragma unroll
        for (int j = 0; j < 4; ++j) {
          const float4 cv = ((const float4*)(cb + (size_t)(lane + 64 * j) * DIM))[kb];
          d[j] = fmaf(rv.x, cv.x, d[j]);
          d[j] = fmaf(rv.y, cv.y, d[j]);
          d[j] = fmaf(rv.z, cv.z, d[j]);
          d[j] = fmaf(rv.w, cv.w, d[j]);
        }
      }
      const float rn = rnorm[row];
      float bv = 3.4e38f; int be = 0;
#pragma unroll
      for (int j = 0; j < 4; ++j) {
        const int e = lane + 64 * j;
        const float v = (rn - 2.0f * d[j]) + cbn[e];
        if (v < bv) { bv = v; be = e; }
      }
#pragma unroll
      for (int m = 1; m < 64; m <<= 1) {
        const float vo = __shfl_xor(bv, m, 64);
        const int   eo = __shfl_xor(be, m, 64);
        if (vo < bv || (vo == bv && eo < be)) { bv = vo; be = eo; }
      }
      if (lane == 0) sIdx[r] = be;
    }
  }
  __syncthreads();

  // ---- update phase: 2 rows/wave x 4 passes (packed stores are natural 16B) ----
  const int half = lane >> 5, j = lane & 31;
  float msum = 0.0f;
  for (int i = 0; i < 4; ++i) {
    const int rr = i * 8 + wave * 2 + half;
    const int row = rbase + rr;
    const int e = sIdx[rr];
    const float4* rp = (const float4*)(src + (size_t)row * DIM + j * 8);
    float4 r0 = rp[0], r1 = rp[1];
    const float4* qp = (const float4*)(cb + (size_t)e * DIM + j * 8);
    float4 q0 = qp[0], q1 = qp[1];
    float nr[8] = {r0.x - q0.x, r0.y - q0.y, r0.z - q0.z, r0.w - q0.w,
                   r1.x - q1.x, r1.y - q1.y, r1.z - q1.z, r1.w - q1.w};
    float ss = 0.f;
#pragma unroll
    for (int u = 0; u < 8; ++u) ss += nr[u] * nr[u];
    if (stage == 3) {
      // x_q = x - resid_final (skip the per-stage xq accumulation entirely)
      const float4* xr = (const float4*)(xin + (size_t)row * DIM + j * 8);
      float4 x0 = xr[0], x1 = xr[1];
      float4* xp = (float4*)(xq + (size_t)row * DIM + j * 8);
      xp[0] = (float4){x0.x - nr[0], x0.y - nr[1], x0.z - nr[2], x0.w - nr[3]};
      xp[1] = (float4){x1.x - nr[4], x1.y - nr[5], x1.z - nr[6], x1.w - nr[7]};
    }
#pragma unroll
    for (int m = 1; m < 32; m <<= 1) ss += __shfl_xor(ss, m, 64);
    if (stage < 3) {
      float4* rw = (float4*)(resid + (size_t)row * DIM + j * 8);
      rw[0] = (float4){nr[0], nr[1], nr[2], nr[3]};
      rw[1] = (float4){nr[4], nr[5], nr[6], nr[7]};
      const float sc = rsqrtf(ss + 1e-12f);
      ushort8v h, l, xn;
#pragma unroll
      for (int u = 0; u < 8; ++u) {
        h[u] = f2bf(nr[u]); l[u] = f2bf(nr[u] - bf2f(h[u])); xn[u] = f2bf(nr[u] * sc);
      }
      const size_t c = chunkIdx(row, j) * 8;
      *(ushort8v*)(rHp + c) = h;
      *(ushort8v*)(rLp + c) = l;
      *(ushort8v*)(Xnp + c) = xn;
      if (j == 0) rnorm[row] = ss;
    }
    if (j == 0) {
      idxf[(size_t)row * NQ + stage] = (float)e;
      msum += ss;
    }
  }
  msum += __shfl_xor(msum, 32, 64);
  if (lane == 0) sred[wave] = msum;
  __syncthreads();
  if (tid == 0) atomicAdd(&acc[0], sred[0] + sred[1] + sred[2] + sred[3]);
}

// ---------------- finalize scalar outputs ----------------
__global__ void finalize_kernel(const float* __restrict__ acc, float* __restrict__ out) {
  const int t = threadIdx.x;
  if (t == 0) out[ND] = acc[0] * (1.25f / (4.0f * (float)ND));
  if (t < 4) out[ND + 1 + t] = acc[4 + t] * (1.0f / (float)KP);
}

extern "C" void kernel_launch(void* const* d_in, const int* in_sizes, int n_in,
                              void* d_out, int out_size, void* d_ws, size_t ws_size,
                              hipStream_t stream) {
  const float* x         = (const float*)d_in[0];
  const float* codebooks = (const float*)d_in[1];
  const int*   i1        = (const int*)d_in[2];
  const int*   i2        = (const int*)d_in[3];
  float* out = (float*)d_out;
  float* out_xq   = out;                 // [N, D]
  float* out_idxf = out + ND + 1 + NQ;   // [N, NQ] as float

  char* w = (char*)d_ws;
  float*          resid = (float*)w;          w += (size_t)N_ROWS * DIM * 4;
  unsigned short* Xnp   = (unsigned short*)w; w += (size_t)N_ROWS * DIM * 2;
  unsigned short* rHp   = (unsigned short*)w; w += (size_t)N_ROWS * DIM * 2;
  unsigned short* rLp   = (unsigned short*)w; w += (size_t)N_ROWS * DIM * 2;
  float*          rnorm = (float*)w;          w += (size_t)N_ROWS * 4;
  unsigned short* Qgp   = (unsigned short*)w; w += (size_t)KP * DIM * 2;
  float*          pos   = (float*)w;          w += (size_t)KP * 4;
  float*          ssum  = (float*)w;          w += (size_t)KP * 4;
  float*          cbn   = (float*)w;          w += (size_t)NQ * NE * 4;
  unsigned short* cbHp  = (unsigned short*)w; w += (size_t)NQ * NE * DIM * 2;
  unsigned short* cbLp  = (unsigned short*)w; w += (size_t)NQ * NE * DIM * 2;
  float*          acc   = (float*)w;          w += 32;  // [0]=sumsq, [4..7]=outer sums

  prep0_kernel<<<4096, 256, 0, stream>>>(x, Xnp, rnorm, rHp, rLp);
  cbnorm_kernel<<<256, 256, 0, stream>>>(codebooks, cbn);
  cbsplit_kernel<<<128, 256, 0, stream>>>(codebooks, cbHp, cbLp);
  hipMemsetAsync(acc, 0, 32, stream);
  for (int q = 0; q < NQ; ++q) {
    const float* cb = codebooks + (size_t)q * NE * DIM;
    gather_pos_kernel<<<1024, 256, 0, stream>>>(Xnp, i1, i2, Qgp, pos, ssum);
    sim_lse_kernel<<<dim3(32, 64), 256, 0, stream>>>(Qgp, Xnp, ssum);
    lse_final_kernel<<<16, 256, 0, stream>>>(ssum, pos, acc, q);
    argmin_update_kernel<<<1024, 256, 0, stream>>>(
        x, resid, cb, cbHp + (size_t)q * NE * DIM, cbLp + (size_t)q * NE * DIM,
        cbn + q * NE, rnorm, rHp, rLp, out_xq, out_idxf, acc, Xnp, q);
  }
  finalize_kernel<<<1, 64, 0, stream>>>(acc, out);
}

// Round 7
// 661.024 us; speedup vs baseline: 1.0167x; 1.0167x over previous
//
#include <hip/hip_runtime.h>

#define N_ROWS 32768
#define DIM    256
#define NE     256
#define KP     4096
#define NQ     4
#define ND     8388608   // N_ROWS*DIM
#define RESCORE_MARGIN 2e-4f

typedef short short8 __attribute__((ext_vector_type(8)));
typedef unsigned short ushort8v __attribute__((ext_vector_type(8)));
typedef float f32x4  __attribute__((ext_vector_type(4)));
typedef float f32x16 __attribute__((ext_vector_type(16)));

__device__ inline float bf2f(unsigned short u) {
  return __uint_as_float(((unsigned)u) << 16);
}
__device__ inline unsigned short f2bf(float f) {
  unsigned u = __float_as_uint(f);
  u += 0x7fffu + ((u >> 16) & 1u);
  return (unsigned short)(u >> 16);
}

// Fragment-major packed layout (16B chunks): chunk (tile*8+f)*64 + quad*16 + l16
// holds row tile*16+l16, dims [f*32+quad*8, +8). For row r, dim chunk j (=k/8):
// index ((r>>4)*8 + (j>>2))*64 + ((j&3)<<4) + (r&15).
// The 16B chunk is the atomic unit: both 16x16x32 fragments (row=l&15,
// j=f*4+(l>>4)) and 32x32x16 fragments (row=l&31, j=2f+(l>>5)) gather from
// this same array via different lane->chunk mappings.
__device__ inline size_t chunkIdx(int row, int j) {
  return (size_t)(((row >> 4) * 8 + (j >> 2)) * 64 + ((j & 3) << 4) + (row & 15));
}

// ---------------- stage 0 prep: packed Xn/rH/rL, rnorm (NO resid copy:
// x_q = x - resid_final identity lets stage 0 read x directly) ----------------
__global__ __launch_bounds__(256) void prep0_kernel(
    const float* __restrict__ x,
    unsigned short* __restrict__ Xnp, float* __restrict__ rnorm,
    unsigned short* __restrict__ rHp, unsigned short* __restrict__ rLp) {
  const int tid = threadIdx.x, wave = tid >> 6, lane = tid & 63;
  const int half = lane >> 5, j = lane & 31;
  const int row = blockIdx.x * 8 + wave * 2 + half;  // grid 4096
  const float4* xr = (const float4*)(x + (size_t)row * DIM + j * 8);
  float4 v0 = xr[0], v1 = xr[1];
  float vv[8] = {v0.x, v0.y, v0.z, v0.w, v1.x, v1.y, v1.z, v1.w};
  float ss = 0.f;
#pragma unroll
  for (int i = 0; i < 8; ++i) ss += vv[i] * vv[i];
#pragma unroll
  for (int m = 1; m < 32; m <<= 1) ss += __shfl_xor(ss, m, 64);
  if (j == 0) rnorm[row] = ss;
  const float sc = rsqrtf(ss + 1e-12f);
  ushort8v h, l, xn;
#pragma unroll
  for (int i = 0; i < 8; ++i) {
    h[i] = f2bf(vv[i]); l[i] = f2bf(vv[i] - bf2f(h[i])); xn[i] = f2bf(vv[i] * sc);
  }
  const size_t c = chunkIdx(row, j) * 8;
  *(ushort8v*)(rHp + c) = h;
  *(ushort8v*)(rLp + c) = l;
  *(ushort8v*)(Xnp + c) = xn;
}

// ---------------- all codebook row norms (NQ*NE rows), once ----------------
__global__ __launch_bounds__(256) void cbnorm_kernel(
    const float* __restrict__ cb, float* __restrict__ cbn) {
  const int wave = threadIdx.x >> 6, lane = threadIdx.x & 63;
  const int e = blockIdx.x * 4 + wave;  // 0..NQ*NE-1
  float4 v = ((const float4*)(cb + (size_t)e * DIM))[lane];
  float ss = v.x * v.x + v.y * v.y + v.z * v.z + v.w * v.w;
#pragma unroll
  for (int m = 1; m < 64; m <<= 1) ss += __shfl_xor(ss, m, 64);
  if (lane == 0) cbn[e] = ss;
}

// ---------------- codebook hi/lo split, packed, all stages, once ----------------
__global__ __launch_bounds__(256) void cbsplit_kernel(
    const float* __restrict__ cb, unsigned short* __restrict__ cbHp,
    unsigned short* __restrict__ cbLp) {
  const int p = blockIdx.x * 256 + threadIdx.x;  // grid 128 -> 32768 chunks
  const int stage = p >> 13, ps = p & 8191;
  const int l16 = ps & 15, quad = (ps >> 4) & 3, kf = (ps >> 6) & 7, et = ps >> 9;
  const int e = et * 16 + l16, k0 = kf * 32 + quad * 8;
  const float* src = cb + ((size_t)(stage * NE + e)) * DIM + k0;
  float4 v0 = ((const float4*)src)[0], v1 = ((const float4*)src)[1];
  float vv[8] = {v0.x, v0.y, v0.z, v0.w, v1.x, v1.y, v1.z, v1.w};
  ushort8v h, l;
#pragma unroll
  for (int i = 0; i < 8; ++i) {
    h[i] = f2bf(vv[i]); l[i] = f2bf(vv[i] - bf2f(h[i]));
  }
  *(ushort8v*)(cbHp + (size_t)p * 8) = h;
  *(ushort8v*)(cbLp + (size_t)p * 8) = l;
}

// ---------------- per-stage: gather xn[i1] (packed Qg) + pos; zero ssum ----------------
__global__ __launch_bounds__(256) void gather_pos_kernel(
    const unsigned short* __restrict__ Xnp, const int* __restrict__ i1,
    const int* __restrict__ i2, unsigned short* __restrict__ Qgp,
    float* __restrict__ pos, float* __restrict__ ssum) {
  if (blockIdx.x < 16) ssum[blockIdx.x * 256 + threadIdx.x] = 0.0f;
  const int wave = threadIdx.x >> 6, lane = threadIdx.x & 63;
  const int k = blockIdx.x * 4 + wave;
  const int a = i1[k], b = i2[k];
  const int j2 = lane >> 1, off = (lane & 1) * 4;
  ushort4 va = *(const ushort4*)(Xnp + chunkIdx(a, j2) * 8 + off);
  ushort4 vb = *(const ushort4*)(Xnp + chunkIdx(b, j2) * 8 + off);
  *(ushort4*)(Qgp + chunkIdx(k, j2) * 8 + off) = va;
  float d = bf2f(va.x) * bf2f(vb.x) + bf2f(va.y) * bf2f(vb.y) +
            bf2f(va.z) * bf2f(vb.z) + bf2f(va.w) * bf2f(vb.w);
#pragma unroll
  for (int m = 1; m < 64; m <<= 1) d += __shfl_xor(d, m, 64);
  if (lane == 0) pos[k] = d * 10.0f;  // /TEMP
}

// ---------------- per-stage: sim GEMM (MFMA) + sum(exp(logit-10)) ----------------
// v7: 2 A-tiles per wave (64 q-rows) -> each LDS b[f] read feeds 2 MFMAs.
// Pipe budget that v3-v6 all hit (serialized): LDSread 41us + MFMA 27.5us +
// VALU 12us = 80.5us == measured 83 (MfmaUtil 27.5/83 = 33% == measured).
// LDS-read bytes = waves x B-bytes; halving blocks (grid 16x64) halves it to
// ~20.5us, under the MFMA term; per-f interleave read->mfma->mfma lets 8
// waves/CU overlap the pipes. A-fragments are PINNED in registers via
// asm "+v" ties (v3-v6's VGPR=64 showed the compiler streaming A from L2
// inside the loop; volatile asm makes rematerialization impossible).
// NOTE: operand-resident design: NEVER >2 in launch_bounds min-waves (r1: a 4
// forced a 64-VGPR cap and spilled 1.5GB to scratch, 7x slower).
__global__ __launch_bounds__(256, 2) void sim_lse_kernel(
    const unsigned short* __restrict__ Qgp, const unsigned short* __restrict__ Xnp,
    float* __restrict__ s_sum) {
  __shared__ unsigned short ldsB[16384];  // 2 buffers x (32 rows x 256 bf16 = 16KB)
  const int tid  = threadIdx.x;
  const int lane = tid & 63;
  const int wave = tid >> 6;
  const int r32  = lane & 31;
  const int h    = lane >> 5;

  // XCD-aware bijective swizzle (hw round-robins flat id over 8 XCDs).
  const int fid = blockIdx.y * 16 + blockIdx.x;   // grid (16, 64) = 1024 blocks
  const int xcd = fid & 7;
  const int sl  = fid >> 3;             // 0..127
  const int bx  = sl & 15;              // q-tile group (256 q-rows)
  const int by  = xcd * 8 + (sl >> 4);  // n-chunk (512 n-rows), contiguous per XCD

  // A: this wave's 2 tiles of 32 q-rows; 16 K-fragments of 16 each.
  // row=r32 of tile, k=(l>>5)*8 within chunk j=2f+h; packed tile stride 4096.
  const unsigned short* abase0 =
      Qgp + (size_t)(bx * 16 + wave * 4 + (r32 >> 4)) * 4096 + h * 128 + (r32 & 15) * 8;
  const unsigned short* abase1 = abase0 + 8192;  // +2 packed tiles
  short8 a0[16], a1[16];
#pragma unroll
  for (int f = 0; f < 16; ++f) {
    a0[f] = *(const short8*)(abase0 + f * 256);
    a1[f] = *(const short8*)(abase1 + f * 256);
  }
  // Pin A resident: volatile asm tie cannot be rematerialized -> no L2 re-reads.
#pragma unroll
  for (int f = 0; f < 16; ++f) {
    asm volatile("" : "+v"(a0[f]));
    asm volatile("" : "+v"(a1[f]));
  }

  float s0[16], s1[16];
#pragma unroll
  for (int i = 0; i < 16; ++i) { s0[i] = 0.f; s1[i] = 0.f; }
  const f32x16 z16 = {0.f, 0.f, 0.f, 0.f, 0.f, 0.f, 0.f, 0.f,
                      0.f, 0.f, 0.f, 0.f, 0.f, 0.f, 0.f, 0.f};
  const float C1 = 14.4269504088896341f;  // 10*log2(e); exp(10d-10)=exp2(d*C1-C1)

  // LDS read base (bytes) for B fragments: row=r32, k-chunk j=2f+h ->
  // byte = (r32>>4)*8192 + h*256 + (r32&15)*16 + f*512.
  const int lbase = (r32 >> 4) * 8192 + h * 256 + (r32 & 15) * 16;

  // Stage group g (32 rows = 2 packed tiles = 16KB contiguous) into buffer pp.
  auto stageB = [&](int g, int pp) {
    const unsigned short* sp =
        Xnp + (size_t)(by * 32 + g * 2) * 4096 + wave * 512 + lane * 8;
    unsigned short* dp = &ldsB[pp * 8192 + wave * 512 + lane * 8];
#pragma unroll
    for (int p = 0; p < 4; ++p)
      __builtin_amdgcn_global_load_lds(
          (const __attribute__((address_space(1))) unsigned int*)(sp + p * 2048),
          (__attribute__((address_space(3))) unsigned int*)(dp + p * 2048),
          16, 0, 0);
  };

  stageB(0, 0);
  for (int g = 0; g < 16; ++g) {
    const int pp = g & 1;
    // own stage(g) landed (issued a full iteration ago); sync all waves:
    // stage(g) complete AND buf[pp^1] reads drained (its MFMAs consumed them).
    asm volatile("s_waitcnt vmcnt(0)" ::: "memory");
    __builtin_amdgcn_s_barrier();
    __builtin_amdgcn_sched_barrier(0);
    if (g + 1 < 16) stageB(g + 1, pp ^ 1);  // async into the other buffer

    const char* bufR = (const char*)&ldsB[pp * 8192];
    f32x16 c0 = z16, c1 = z16;  // 2 independent chains (one per A-tile)
#pragma unroll
    for (int f = 0; f < 16; ++f) {
      short8 b = *(const short8*)(bufR + lbase + f * 512);
      c0 = __builtin_amdgcn_mfma_f32_32x32x16_bf16(a0[f], b, c0, 0, 0, 0);
      c1 = __builtin_amdgcn_mfma_f32_32x32x16_bf16(a1[f], b, c1, 0, 0, 0);
    }
#pragma unroll
    for (int i = 0; i < 16; ++i) {
      s0[i] += exp2f(fmaf(c0[i], C1, -C1));
      s1[i] += exp2f(fmaf(c1[i], C1, -C1));
    }
  }

  // sum over 32 n-cols (lane&31); rows live per (reg, half-wave).
#pragma unroll
  for (int m = 1; m < 32; m <<= 1)
#pragma unroll
    for (int i = 0; i < 16; ++i) {
      s0[i] += __shfl_xor(s0[i], m, 64);
      s1[i] += __shfl_xor(s1[i], m, 64);
    }
  if (r32 == 0) {
    const int qb = bx * 256 + wave * 64;
#pragma unroll
    for (int i = 0; i < 16; ++i) {
      const int row = (i & 3) + 8 * (i >> 2) + 4 * h;  // C layout m74/m101
      atomicAdd(&s_sum[qb + row], s0[i]);
      atomicAdd(&s_sum[qb + 32 + row], s1[i]);
    }
  }
}

// ---------------- per-stage: lse -> outer loss accumulator ----------------
__global__ __launch_bounds__(256) void lse_final_kernel(
    const float* __restrict__ s_sum, const float* __restrict__ pos,
    float* __restrict__ acc, int stage) {
  const int t = threadIdx.x;
  const int k = blockIdx.x * 256 + t;
  float v = 10.0f + __logf(s_sum[k]) - pos[k];
#pragma unroll
  for (int m = 1; m < 64; m <<= 1) v += __shfl_xor(v, m, 64);
  __shared__ float red[4];
  if ((t & 63) == 0) red[t >> 6] = v;
  __syncthreads();
  if (t == 0) atomicAdd(&acc[4 + stage], red[0] + red[1] + red[2] + red[3]);
}

// ---------------- per-stage: MFMA argmin (hi/lo) + fp32 rescore + update ----------------
// 32 rows/block (grid 1024). Packed operands, kf-loop register ping-pong.
// Memory-traffic notes:
//  - stage 0 reads residual from x directly (no x->resid copy)
//  - xq is NOT accumulated: x_q = x - resid_final; stage 3 writes xq = x - nr.
__global__ __launch_bounds__(256, 2) void argmin_update_kernel(
    const float* __restrict__ xin, float* __restrict__ resid,
    const float* __restrict__ cb,
    const unsigned short* __restrict__ cbHp, const unsigned short* __restrict__ cbLp,
    const float* __restrict__ cbn, float* __restrict__ rnorm,
    unsigned short* rHp, unsigned short* rLp,
    float* __restrict__ xq, float* __restrict__ idxf, float* __restrict__ acc,
    unsigned short* __restrict__ Xnp, int stage) {
  __shared__ float sV1[4][32];
  __shared__ float sV2[4][32];
  __shared__ int   sIx[4][32];
  __shared__ int   sIdx[32];
  __shared__ int   sFlag[32];
  __shared__ float sred[4];
  const int tid  = threadIdx.x;
  const int lane = tid & 63;
  const int wave = tid >> 6;
  const int quad = lane >> 4;
  const int l16  = lane & 15;
  const int rbase = blockIdx.x * 32;
  const int t0 = blockIdx.x * 2;
  const float* __restrict__ src = (stage == 0) ? xin : resid;  // current residual

  f32x4 acc4[2][4];  // [rt][ct] : row rt*16+quad*4+i, e (wave*4+ct)*16+l16
#pragma unroll
  for (int rt = 0; rt < 2; ++rt)
#pragma unroll
    for (int ct = 0; ct < 4; ++ct) acc4[rt][ct] = (f32x4){0.f, 0.f, 0.f, 0.f};

  auto loadA = [&](int kf, short8 (&aH)[2], short8 (&aL)[2]) {
#pragma unroll
    for (int rt = 0; rt < 2; ++rt) {
      const size_t off = ((size_t)(((t0 + rt) * 8 + kf) * 64 + lane)) * 8;
      aH[rt] = *(const short8*)(rHp + off);
      aL[rt] = *(const short8*)(rLp + off);
    }
  };
  auto loadBc = [&](int kf, short8 (&bH)[4], short8 (&bL)[4]) {
#pragma unroll
    for (int ct = 0; ct < 4; ++ct) {
      const size_t boff = ((size_t)(((wave * 4 + ct) * 8 + kf) * 64 + lane)) * 8;
      bH[ct] = *(const short8*)(cbHp + boff);
      bL[ct] = *(const short8*)(cbLp + boff);
    }
  };
  auto computeK = [&](short8 (&aH)[2], short8 (&aL)[2], short8 (&bH)[4],
                      short8 (&bL)[4]) {
#pragma unroll
    for (int ct = 0; ct < 4; ++ct)
#pragma unroll
      for (int rt = 0; rt < 2; ++rt) {
        acc4[rt][ct] = __builtin_amdgcn_mfma_f32_16x16x32_bf16(aL[rt], bH[ct], acc4[rt][ct], 0, 0, 0);
        acc4[rt][ct] = __builtin_amdgcn_mfma_f32_16x16x32_bf16(aH[rt], bL[ct], acc4[rt][ct], 0, 0, 0);
        acc4[rt][ct] = __builtin_amdgcn_mfma_f32_16x16x32_bf16(aH[rt], bH[ct], acc4[rt][ct], 0, 0, 0);
      }
  };

  short8 aH0[2], aL0[2], bH0[4], bL0[4], aH1[2], aL1[2], bH1[4], bL1[4];
  loadA(0, aH0, aL0); loadBc(0, bH0, bL0);
  for (int kf = 0; kf < 8; kf += 2) {
    loadA(kf + 1, aH1, aL1); loadBc(kf + 1, bH1, bL1);
    computeK(aH0, aL0, bH0, bL0);
    if (kf + 2 < 8) { loadA(kf + 2, aH0, aL0); loadBc(kf + 2, bH0, bL0); }
    computeK(aH1, aL1, bH1, bL1);
  }

  // ---- epilogue: per-row top-2 over this wave's 64 e ----
  float cbe[4];
#pragma unroll
  for (int ct = 0; ct < 4; ++ct) cbe[ct] = cbn[(wave * 4 + ct) * 16 + l16];
#pragma unroll
  for (int rt = 0; rt < 2; ++rt) {
    float b1[4], b2[4]; int e1[4];
#pragma unroll
    for (int i = 0; i < 4; ++i) { b1[i] = 3.4e38f; b2[i] = 3.4e38f; e1[i] = 0; }
#pragma unroll
    for (int ct = 0; ct < 4; ++ct) {
      const int e = (wave * 4 + ct) * 16 + l16;
#pragma unroll
      for (int i = 0; i < 4; ++i) {
        const float v = fmaf(-2.0f, acc4[rt][ct][i], cbe[ct]);
        if (v < b1[i]) { b2[i] = b1[i]; b1[i] = v; e1[i] = e; }
        else if (v < b2[i]) b2[i] = v;
      }
    }
#pragma unroll
    for (int m = 1; m < 16; m <<= 1) {
#pragma unroll
      for (int i = 0; i < 4; ++i) {
        const float o1 = __shfl_xor(b1[i], m, 64);
        const float o2 = __shfl_xor(b2[i], m, 64);
        const int   oe = __shfl_xor(e1[i], m, 64);
        if (o1 < b1[i] || (o1 == b1[i] && oe < e1[i])) {
          b2[i] = fminf(b1[i], o2); b1[i] = o1; e1[i] = oe;
        } else {
          b2[i] = fminf(b2[i], o1);
        }
      }
    }
    if (l16 == 0) {
#pragma unroll
      for (int i = 0; i < 4; ++i) {
        const int r = rt * 16 + quad * 4 + i;
        sV1[wave][r] = b1[i]; sV2[wave][r] = b2[i]; sIx[wave][r] = e1[i];
      }
    }
  }
  __syncthreads();
  if (tid < 32) {
    float v1 = 3.4e38f, v2 = 3.4e38f; int ix = 0;
#pragma unroll
    for (int w = 0; w < 4; ++w) {
      const float a1 = sV1[w][tid], a2 = sV2[w][tid];
      const int ae = sIx[w][tid];
      if (a1 < v1) { v2 = fminf(v1, a2); v1 = a1; ix = ae; }
      else { v2 = fminf(v2, fminf(a1, a2)); }
    }
    sIdx[tid] = ix;
    sFlag[tid] = (v2 - v1 < RESCORE_MARGIN) ? 1 : 0;
  }
  __syncthreads();

  // ---- exact fp32 rescore for flagged rows (rare) ----
  for (int rr = 0; rr < 8; ++rr) {
    const int r = wave * 8 + rr;
    if (sFlag[r]) {
      const int row = rbase + r;
      const float* rrow = src + (size_t)row * DIM;
      float d[4] = {0.f, 0.f, 0.f, 0.f};
      for (int kb = 0; kb < 64; ++kb) {
        const float4 rv = ((const float4*)rrow)[kb];
#pragma unroll
        for (int j = 0; j < 4; ++j) {
          const float4 cv = ((const float4*)(cb + (size_t)(lane + 64 * j) * DIM))[kb];
          d[j] = fmaf(rv.x, cv.x, d[j]);
          d[j] = fmaf(rv.y, cv.y, d[j]);
          d[j] = fmaf(rv.z, cv.z, d[j]);
          d[j] = fmaf(rv.w, cv.w, d[j]);
        }
      }
      const float rn = rnorm[row];
      float bv = 3.4e38f; int be = 0;
#pragma unroll
      for (int j = 0; j < 4; ++j) {
        const int e = lane + 64 * j;
        const float v = (rn - 2.0f * d[j]) + cbn[e];
        if (v < bv) { bv = v; be = e; }
      }
#pragma unroll
      for (int m = 1; m < 64; m <<= 1) {
        const float vo = __shfl_xor(bv, m, 64);
        const int   eo = __shfl_xor(be, m, 64);
        if (vo < bv || (vo == bv && eo < be)) { bv = vo; be = eo; }
      }
      if (lane == 0) sIdx[r] = be;
    }
  }
  __syncthreads();

  // ---- update phase: 2 rows/wave x 4 passes (packed stores are natural 16B) ----
  const int half = lane >> 5, j = lane & 31;
  float msum = 0.0f;
  for (int i = 0; i < 4; ++i) {
    const int rr = i * 8 + wave * 2 + half;
    const int row = rbase + rr;
    const int e = sIdx[rr];
    const float4* rp = (const float4*)(src + (size_t)row * DIM + j * 8);
    float4 r0 = rp[0], r1 = rp[1];
    const float4* qp = (const float4*)(cb + (size_t)e * DIM + j * 8);
    float4 q0 = qp[0], q1 = qp[1];
    float nr[8] = {r0.x - q0.x, r0.y - q0.y, r0.z - q0.z, r0.w - q0.w,
                   r1.x - q1.x, r1.y - q1.y, r1.z - q1.z, r1.w - q1.w};
    float ss = 0.f;
#pragma unroll
    for (int u = 0; u < 8; ++u) ss += nr[u] * nr[u];
    if (stage == 3) {
      // x_q = x - resid_final (skip the per-stage xq accumulation entirely)
      const float4* xr = (const float4*)(xin + (size_t)row * DIM + j * 8);
      float4 x0 = xr[0], x1 = xr[1];
      float4* xp = (float4*)(xq + (size_t)row * DIM + j * 8);
      xp[0] = (float4){x0.x - nr[0], x0.y - nr[1], x0.z - nr[2], x0.w - nr[3]};
      xp[1] = (float4){x1.x - nr[4], x1.y - nr[5], x1.z - nr[6], x1.w - nr[7]};
    }
#pragma unroll
    for (int m = 1; m < 32; m <<= 1) ss += __shfl_xor(ss, m, 64);
    if (stage < 3) {
      float4* rw = (float4*)(resid + (size_t)row * DIM + j * 8);
      rw[0] = (float4){nr[0], nr[1], nr[2], nr[3]};
      rw[1] = (float4){nr[4], nr[5], nr[6], nr[7]};
      const float sc = rsqrtf(ss + 1e-12f);
      ushort8v h, l, xn;
#pragma unroll
      for (int u = 0; u < 8; ++u) {
        h[u] = f2bf(nr[u]); l[u] = f2bf(nr[u] - bf2f(h[u])); xn[u] = f2bf(nr[u] * sc);
      }
      const size_t c = chunkIdx(row, j) * 8;
      *(ushort8v*)(rHp + c) = h;
      *(ushort8v*)(rLp + c) = l;
      *(ushort8v*)(Xnp + c) = xn;
      if (j == 0) rnorm[row] = ss;
    }
    if (j == 0) {
      idxf[(size_t)row * NQ + stage] = (float)e;
      msum += ss;
    }
  }
  msum += __shfl_xor(msum, 32, 64);
  if (lane == 0) sred[wave] = msum;
  __syncthreads();
  if (tid == 0) atomicAdd(&acc[0], sred[0] + sred[1] + sred[2] + sred[3]);
}

// ---------------- finalize scalar outputs ----------------
__global__ void finalize_kernel(const float* __restrict__ acc, float* __restrict__ out) {
  const int t = threadIdx.x;
  if (t == 0) out[ND] = acc[0] * (1.25f / (4.0f * (float)ND));
  if (t < 4) out[ND + 1 + t] = acc[4 + t] * (1.0f / (float)KP);
}

extern "C" void kernel_launch(void* const* d_in, const int* in_sizes, int n_in,
                              void* d_out, int out_size, void* d_ws, size_t ws_size,
                              hipStream_t stream) {
  const float* x         = (const float*)d_in[0];
  const float* codebooks = (const float*)d_in[1];
  const int*   i1        = (const int*)d_in[2];
  const int*   i2        = (const int*)d_in[3];
  float* out = (float*)d_out;
  float* out_xq   = out;                 // [N, D]
  float* out_idxf = out + ND + 1 + NQ;   // [N, NQ] as float

  char* w = (char*)d_ws;
  float*          resid = (float*)w;          w += (size_t)N_ROWS * DIM * 4;
  unsigned short* Xnp   = (unsigned short*)w; w += (size_t)N_ROWS * DIM * 2;
  unsigned short* rHp   = (unsigned short*)w; w += (size_t)N_ROWS * DIM * 2;
  unsigned short* rLp   = (unsigned short*)w; w += (size_t)N_ROWS * DIM * 2;
  float*          rnorm = (float*)w;          w += (size_t)N_ROWS * 4;
  unsigned short* Qgp   = (unsigned short*)w; w += (size_t)KP * DIM * 2;
  float*          pos   = (float*)w;          w += (size_t)KP * 4;
  float*          ssum  = (float*)w;          w += (size_t)KP * 4;
  float*          cbn   = (float*)w;          w += (size_t)NQ * NE * 4;
  unsigned short* cbHp  = (unsigned short*)w; w += (size_t)NQ * NE * DIM * 2;
  unsigned short* cbLp  = (unsigned short*)w; w += (size_t)NQ * NE * DIM * 2;
  float*          acc   = (float*)w;          w += 32;  // [0]=sumsq, [4..7]=outer sums

  prep0_kernel<<<4096, 256, 0, stream>>>(x, Xnp, rnorm, rHp, rLp);
  cbnorm_kernel<<<256, 256, 0, stream>>>(codebooks, cbn);
  cbsplit_kernel<<<128, 256, 0, stream>>>(codebooks, cbHp, cbLp);
  hipMemsetAsync(acc, 0, 32, stream);
  for (int q = 0; q < NQ; ++q) {
    const float* cb = codebooks + (size_t)q * NE * DIM;
    gather_pos_kernel<<<1024, 256, 0, stream>>>(Xnp, i1, i2, Qgp, pos, ssum);
    sim_lse_kernel<<<dim3(16, 64), 256, 0, stream>>>(Qgp, Xnp, ssum);
    lse_final_kernel<<<16, 256, 0, stream>>>(ssum, pos, acc, q);
    argmin_update_kernel<<<1024, 256, 0, stream>>>(
        x, resid, cb, cbHp + (size_t)q * NE * DIM, cbLp + (size_t)q * NE * DIM,
        cbn + q * NE, rnorm, rHp, rLp, out_xq, out_idxf, acc, Xnp, q);
  }
  finalize_kernel<<<1, 64, 0, stream>>>(acc, out);
}

// Round 8
// 617.004 us; speedup vs baseline: 1.0892x; 1.0713x over previous
//
#include <hip/hip_runtime.h>

#define N_ROWS 32768
#define DIM    256
#define NE     256
#define KP     4096
#define NQ     4
#define ND     8388608   // N_ROWS*DIM
#define RESCORE_MARGIN 2e-4f

typedef short short8 __attribute__((ext_vector_type(8)));
typedef unsigned short ushort8v __attribute__((ext_vector_type(8)));
typedef float f32x4  __attribute__((ext_vector_type(4)));

__device__ inline float bf2f(unsigned short u) {
  return __uint_as_float(((unsigned)u) << 16);
}
__device__ inline unsigned short f2bf(float f) {
  unsigned u = __float_as_uint(f);
  u += 0x7fffu + ((u >> 16) & 1u);
  return (unsigned short)(u >> 16);
}
// Raw v_exp_f32: args here are in [-29, 0] -> results are normal floats, so
// OCML's denormal-safe exp2 sequence (several VALU ops) is pure overhead.
__device__ inline float fexp2(float x) { return __builtin_amdgcn_exp2f(x); }

// Fragment-major packed layout (16B chunks): chunk (tile*8+f)*64 + quad*16 + l16
// holds row tile*16+l16, dims [f*32+quad*8, +8). For row r, dim chunk j (=k/8):
// index ((r>>4)*8 + (j>>2))*64 + ((j&3)<<4) + (r&15).
__device__ inline size_t chunkIdx(int row, int j) {
  return (size_t)(((row >> 4) * 8 + (j >> 2)) * 64 + ((j & 3) << 4) + (row & 15));
}

// ---------------- stage 0 prep: packed Xn/rH/rL, rnorm (NO resid copy:
// x_q = x - resid_final identity lets stage 0 read x directly) ----------------
__global__ __launch_bounds__(256) void prep0_kernel(
    const float* __restrict__ x,
    unsigned short* __restrict__ Xnp, float* __restrict__ rnorm,
    unsigned short* __restrict__ rHp, unsigned short* __restrict__ rLp) {
  const int tid = threadIdx.x, wave = tid >> 6, lane = tid & 63;
  const int half = lane >> 5, j = lane & 31;
  const int row = blockIdx.x * 8 + wave * 2 + half;  // grid 4096
  const float4* xr = (const float4*)(x + (size_t)row * DIM + j * 8);
  float4 v0 = xr[0], v1 = xr[1];
  float vv[8] = {v0.x, v0.y, v0.z, v0.w, v1.x, v1.y, v1.z, v1.w};
  float ss = 0.f;
#pragma unroll
  for (int i = 0; i < 8; ++i) ss += vv[i] * vv[i];
#pragma unroll
  for (int m = 1; m < 32; m <<= 1) ss += __shfl_xor(ss, m, 64);
  if (j == 0) rnorm[row] = ss;
  const float sc = rsqrtf(ss + 1e-12f);
  ushort8v h, l, xn;
#pragma unroll
  for (int i = 0; i < 8; ++i) {
    h[i] = f2bf(vv[i]); l[i] = f2bf(vv[i] - bf2f(h[i])); xn[i] = f2bf(vv[i] * sc);
  }
  const size_t c = chunkIdx(row, j) * 8;
  *(ushort8v*)(rHp + c) = h;
  *(ushort8v*)(rLp + c) = l;
  *(ushort8v*)(Xnp + c) = xn;
}

// ---------------- all codebook row norms (NQ*NE rows), once ----------------
__global__ __launch_bounds__(256) void cbnorm_kernel(
    const float* __restrict__ cb, float* __restrict__ cbn) {
  const int wave = threadIdx.x >> 6, lane = threadIdx.x & 63;
  const int e = blockIdx.x * 4 + wave;  // 0..NQ*NE-1
  float4 v = ((const float4*)(cb + (size_t)e * DIM))[lane];
  float ss = v.x * v.x + v.y * v.y + v.z * v.z + v.w * v.w;
#pragma unroll
  for (int m = 1; m < 64; m <<= 1) ss += __shfl_xor(ss, m, 64);
  if (lane == 0) cbn[e] = ss;
}

// ---------------- codebook hi/lo split, packed, all stages, once ----------------
__global__ __launch_bounds__(256) void cbsplit_kernel(
    const float* __restrict__ cb, unsigned short* __restrict__ cbHp,
    unsigned short* __restrict__ cbLp) {
  const int p = blockIdx.x * 256 + threadIdx.x;  // grid 128 -> 32768 chunks
  const int stage = p >> 13, ps = p & 8191;
  const int l16 = ps & 15, quad = (ps >> 4) & 3, kf = (ps >> 6) & 7, et = ps >> 9;
  const int e = et * 16 + l16, k0 = kf * 32 + quad * 8;
  const float* src = cb + ((size_t)(stage * NE + e)) * DIM + k0;
  float4 v0 = ((const float4*)src)[0], v1 = ((const float4*)src)[1];
  float vv[8] = {v0.x, v0.y, v0.z, v0.w, v1.x, v1.y, v1.z, v1.w};
  ushort8v h, l;
#pragma unroll
  for (int i = 0; i < 8; ++i) {
    h[i] = f2bf(vv[i]); l[i] = f2bf(vv[i] - bf2f(h[i]));
  }
  *(ushort8v*)(cbHp + (size_t)p * 8) = h;
  *(ushort8v*)(cbLp + (size_t)p * 8) = l;
}

// ---------------- per-stage: gather xn[i1] (packed Qg) + pos; zero ssum ----------------
__global__ __launch_bounds__(256) void gather_pos_kernel(
    const unsigned short* __restrict__ Xnp, const int* __restrict__ i1,
    const int* __restrict__ i2, unsigned short* __restrict__ Qgp,
    float* __restrict__ pos, float* __restrict__ ssum) {
  if (blockIdx.x < 16) ssum[blockIdx.x * 256 + threadIdx.x] = 0.0f;
  const int wave = threadIdx.x >> 6, lane = threadIdx.x & 63;
  const int k = blockIdx.x * 4 + wave;
  const int a = i1[k], b = i2[k];
  const int j2 = lane >> 1, off = (lane & 1) * 4;
  ushort4 va = *(const ushort4*)(Xnp + chunkIdx(a, j2) * 8 + off);
  ushort4 vb = *(const ushort4*)(Xnp + chunkIdx(b, j2) * 8 + off);
  *(ushort4*)(Qgp + chunkIdx(k, j2) * 8 + off) = va;
  float d = bf2f(va.x) * bf2f(vb.x) + bf2f(va.y) * bf2f(vb.y) +
            bf2f(va.z) * bf2f(vb.z) + bf2f(va.w) * bf2f(vb.w);
#pragma unroll
  for (int m = 1; m < 64; m <<= 1) d += __shfl_xor(d, m, 64);
  if (lane == 0) pos[k] = d * 10.0f;  // /TEMP
}

// ---------------- per-stage: sim GEMM (MFMA) + sum(exp(logit-10)) ----------------
// grid (32 qtiles of 128, 64 n-chunks of 512); block ids XCD-swizzled so XCD k
// owns n-chunks [8k, 8k+8) (L2-resident B+Qgp; FETCH 67->16 MB measured).
// B shared across the 4 waves via LDS (global_load_lds width=16); single 8KB
// buffer. BEST MEASURED schedule of 5 tried (80.2us): reg-pingpong 92.6,
// dbuf+counted-vmcnt 83.5, 32-row dbuf 32x32 MFMA 83.0, 2-tile/wave pinned-A
// 85.5 (occupancy 35->19% ate the LDS-read halving). The kernel is
// latency-bound; occupancy (VGPR 64, LDS 8KB -> 35%) is what matters, not
// per-pipe totals. Only remaining lever applied: raw v_exp_f32 for the tail.
// NOTE: operand-resident design: NEVER >2 in launch_bounds min-waves (r1: a 4
// forced a 64-VGPR cap and spilled 1.5GB to scratch, 7x slower).
__global__ __launch_bounds__(256, 2) void sim_lse_kernel(
    const unsigned short* __restrict__ Qgp, const unsigned short* __restrict__ Xnp,
    float* __restrict__ s_sum) {
  __shared__ unsigned short ldsB[4096];  // one 16-row group: 16 x 256 bf16 = 8KB
  const int tid  = threadIdx.x;
  const int lane = tid & 63;
  const int wave = tid >> 6;
  const int quad = lane >> 4;
  const int l16  = lane & 15;

  // XCD-aware bijective swizzle of the flat workgroup id (hw id = y*32+x,
  // round-robin over 8 XCDs => xcd = fid & 7).
  const int fid = blockIdx.y * 32 + blockIdx.x;
  const int xcd = fid & 7;
  const int sl  = fid >> 3;             // 0..255 per-XCD slot
  const int bx  = sl & 31;              // q-tile group 0..31 (fast: reuses B chunk)
  const int by  = xcd * 8 + (sl >> 5);  // n-chunk 0..63, contiguous range per XCD

  const int qt0  = bx * 8 + wave * 2;
  const int qbase = bx * 128 + wave * 32;

  short8 a[2][8];
#pragma unroll
  for (int t = 0; t < 2; ++t)
#pragma unroll
    for (int f = 0; f < 8; ++f)
      a[t][f] = *(const short8*)(Qgp + ((size_t)(((qt0 + t) * 8 + f) * 64 + lane)) * 8);

  float s[2][4] = {};
  const float C1 = 14.4269504088896341f;  // 10*log2(e); exp(10d-10)=exp2(d*C1-C1)
  const unsigned short* bsrc = Xnp + (size_t)(by * 32) * 4096;

  // Stage group g (8KB, linear copy) into ldsB: each wave moves 2KB as 2x
  // (64 lanes x 16B) ops. LDS dest is wave-uniform base + lane*16 (HW rule).
  auto stageB = [&](int g) {
    const unsigned short* src = bsrc + (size_t)g * 4096 + wave * 1024 + lane * 8;
#pragma unroll
    for (int p = 0; p < 2; ++p)
      __builtin_amdgcn_global_load_lds(
          (const __attribute__((address_space(1))) unsigned int*)(src + p * 512),
          (__attribute__((address_space(3))) unsigned int*)(&ldsB[wave * 1024 + p * 512]),
          16, 0, 0);
  };

  stageB(0);
  for (int g = 0; g < 32; ++g) {
    // staging for g complete (also drains A-loads on first iter), all waves sync
    asm volatile("s_waitcnt vmcnt(0)" ::: "memory");
    __builtin_amdgcn_s_barrier();
    __builtin_amdgcn_sched_barrier(0);
    short8 b[8];
#pragma unroll
    for (int f = 0; f < 8; ++f)
      b[f] = *(const short8*)(&ldsB[f * 512 + lane * 8]);
    asm volatile("s_waitcnt lgkmcnt(0)" ::: "memory");
    __builtin_amdgcn_s_barrier();   // all waves drained their reads -> LDS free
    __builtin_amdgcn_sched_barrier(0);
    if (g + 1 < 32) stageB(g + 1);  // async; covered by MFMA+tail below

    // split K in halves: 4 independent chains of depth 4 (t x half)
    f32x4 acc0[2] = {{0.f, 0.f, 0.f, 0.f}, {0.f, 0.f, 0.f, 0.f}};
    f32x4 acc1[2] = {{0.f, 0.f, 0.f, 0.f}, {0.f, 0.f, 0.f, 0.f}};
#pragma unroll
    for (int f = 0; f < 4; ++f)
#pragma unroll
      for (int t = 0; t < 2; ++t) {
        acc0[t] = __builtin_amdgcn_mfma_f32_16x16x32_bf16(a[t][f], b[f], acc0[t], 0, 0, 0);
        acc1[t] = __builtin_amdgcn_mfma_f32_16x16x32_bf16(a[t][f + 4], b[f + 4], acc1[t], 0, 0, 0);
      }
#pragma unroll
    for (int t = 0; t < 2; ++t) {
      f32x4 m = acc0[t] + acc1[t];
#pragma unroll
      for (int i = 0; i < 4; ++i)
        s[t][i] += fexp2(fmaf(m[i], C1, -C1));
    }
  }
#pragma unroll
  for (int m = 1; m < 16; m <<= 1)
#pragma unroll
    for (int t = 0; t < 2; ++t)
#pragma unroll
      for (int i = 0; i < 4; ++i) s[t][i] += __shfl_xor(s[t][i], m, 64);
  if (l16 == 0) {
#pragma unroll
    for (int t = 0; t < 2; ++t)
#pragma unroll
      for (int i = 0; i < 4; ++i)
        atomicAdd(&s_sum[qbase + t * 16 + quad * 4 + i], s[t][i]);
  }
}

// ---------------- per-stage: lse -> outer loss accumulator ----------------
__global__ __launch_bounds__(256) void lse_final_kernel(
    const float* __restrict__ s_sum, const float* __restrict__ pos,
    float* __restrict__ acc, int stage) {
  const int t = threadIdx.x;
  const int k = blockIdx.x * 256 + t;
  float v = 10.0f + __logf(s_sum[k]) - pos[k];
#pragma unroll
  for (int m = 1; m < 64; m <<= 1) v += __shfl_xor(v, m, 64);
  __shared__ float red[4];
  if ((t & 63) == 0) red[t >> 6] = v;
  __syncthreads();
  if (t == 0) atomicAdd(&acc[4 + stage], red[0] + red[1] + red[2] + red[3]);
}

// ---------------- per-stage: MFMA argmin (hi/lo) + fp32 rescore + update ----------------
// 32 rows/block (grid 1024). Packed operands, kf-loop register ping-pong.
// Memory-traffic notes:
//  - stage 0 reads residual from x directly (no x->resid copy)
//  - xq is NOT accumulated: x_q = x - resid_final; stage 3 writes xq = x - nr.
__global__ __launch_bounds__(256, 2) void argmin_update_kernel(
    const float* __restrict__ xin, float* __restrict__ resid,
    const float* __restrict__ cb,
    const unsigned short* __restrict__ cbHp, const unsigned short* __restrict__ cbLp,
    const float* __restrict__ cbn, float* __restrict__ rnorm,
    unsigned short* rHp, unsigned short* rLp,
    float* __restrict__ xq, float* __restrict__ idxf, float* __restrict__ acc,
    unsigned short* __restrict__ Xnp, int stage) {
  __shared__ float sV1[4][32];
  __shared__ float sV2[4][32];
  __shared__ int   sIx[4][32];
  __shared__ int   sIdx[32];
  __shared__ int   sFlag[32];
  __shared__ float sred[4];
  const int tid  = threadIdx.x;
  const int lane = tid & 63;
  const int wave = tid >> 6;
  const int quad = lane >> 4;
  const int l16  = lane & 15;
  const int rbase = blockIdx.x * 32;
  const int t0 = blockIdx.x * 2;
  const float* __restrict__ src = (stage == 0) ? xin : resid;  // current residual

  f32x4 acc4[2][4];  // [rt][ct] : row rt*16+quad*4+i, e (wave*4+ct)*16+l16
#pragma unroll
  for (int rt = 0; rt < 2; ++rt)
#pragma unroll
    for (int ct = 0; ct < 4; ++ct) acc4[rt][ct] = (f32x4){0.f, 0.f, 0.f, 0.f};

  auto loadA = [&](int kf, short8 (&aH)[2], short8 (&aL)[2]) {
#pragma unroll
    for (int rt = 0; rt < 2; ++rt) {
      const size_t off = ((size_t)(((t0 + rt) * 8 + kf) * 64 + lane)) * 8;
      aH[rt] = *(const short8*)(rHp + off);
      aL[rt] = *(const short8*)(rLp + off);
    }
  };
  auto loadBc = [&](int kf, short8 (&bH)[4], short8 (&bL)[4]) {
#pragma unroll
    for (int ct = 0; ct < 4; ++ct) {
      const size_t boff = ((size_t)(((wave * 4 + ct) * 8 + kf) * 64 + lane)) * 8;
      bH[ct] = *(const short8*)(cbHp + boff);
      bL[ct] = *(const short8*)(cbLp + boff);
    }
  };
  auto computeK = [&](short8 (&aH)[2], short8 (&aL)[2], short8 (&bH)[4],
                      short8 (&bL)[4]) {
#pragma unroll
    for (int ct = 0; ct < 4; ++ct)
#pragma unroll
      for (int rt = 0; rt < 2; ++rt) {
        acc4[rt][ct] = __builtin_amdgcn_mfma_f32_16x16x32_bf16(aL[rt], bH[ct], acc4[rt][ct], 0, 0, 0);
        acc4[rt][ct] = __builtin_amdgcn_mfma_f32_16x16x32_bf16(aH[rt], bL[ct], acc4[rt][ct], 0, 0, 0);
        acc4[rt][ct] = __builtin_amdgcn_mfma_f32_16x16x32_bf16(aH[rt], bH[ct], acc4[rt][ct], 0, 0, 0);
      }
  };

  short8 aH0[2], aL0[2], bH0[4], bL0[4], aH1[2], aL1[2], bH1[4], bL1[4];
  loadA(0, aH0, aL0); loadBc(0, bH0, bL0);
  for (int kf = 0; kf < 8; kf += 2) {
    loadA(kf + 1, aH1, aL1); loadBc(kf + 1, bH1, bL1);
    computeK(aH0, aL0, bH0, bL0);
    if (kf + 2 < 8) { loadA(kf + 2, aH0, aL0); loadBc(kf + 2, bH0, bL0); }
    computeK(aH1, aL1, bH1, bL1);
  }

  // ---- epilogue: per-row top-2 over this wave's 64 e ----
  float cbe[4];
#pragma unroll
  for (int ct = 0; ct < 4; ++ct) cbe[ct] = cbn[(wave * 4 + ct) * 16 + l16];
#pragma unroll
  for (int rt = 0; rt < 2; ++rt) {
    float b1[4], b2[4]; int e1[4];
#pragma unroll
    for (int i = 0; i < 4; ++i) { b1[i] = 3.4e38f; b2[i] = 3.4e38f; e1[i] = 0; }
#pragma unroll
    for (int ct = 0; ct < 4; ++ct) {
      const int e = (wave * 4 + ct) * 16 + l16;
#pragma unroll
      for (int i = 0; i < 4; ++i) {
        const float v = fmaf(-2.0f, acc4[rt][ct][i], cbe[ct]);
        if (v < b1[i]) { b2[i] = b1[i]; b1[i] = v; e1[i] = e; }
        else if (v < b2[i]) b2[i] = v;
      }
    }
#pragma unroll
    for (int m = 1; m < 16; m <<= 1) {
#pragma unroll
      for (int i = 0; i < 4; ++i) {
        const float o1 = __shfl_xor(b1[i], m, 64);
        const float o2 = __shfl_xor(b2[i], m, 64);
        const int   oe = __shfl_xor(e1[i], m, 64);
        if (o1 < b1[i] || (o1 == b1[i] && oe < e1[i])) {
          b2[i] = fminf(b1[i], o2); b1[i] = o1; e1[i] = oe;
        } else {
          b2[i] = fminf(b2[i], o1);
        }
      }
    }
    if (l16 == 0) {
#pragma unroll
      for (int i = 0; i < 4; ++i) {
        const int r = rt * 16 + quad * 4 + i;
        sV1[wave][r] = b1[i]; sV2[wave][r] = b2[i]; sIx[wave][r] = e1[i];
      }
    }
  }
  __syncthreads();
  if (tid < 32) {
    float v1 = 3.4e38f, v2 = 3.4e38f; int ix = 0;
#pragma unroll
    for (int w = 0; w < 4; ++w) {
      const float a1 = sV1[w][tid], a2 = sV2[w][tid];
      const int ae = sIx[w][tid];
      if (a1 < v1) { v2 = fminf(v1, a2); v1 = a1; ix = ae; }
      else { v2 = fminf(v2, fminf(a1, a2)); }
    }
    sIdx[tid] = ix;
    sFlag[tid] = (v2 - v1 < RESCORE_MARGIN) ? 1 : 0;
  }
  __syncthreads();

  // ---- exact fp32 rescore for flagged rows (rare) ----
  for (int rr = 0; rr < 8; ++rr) {
    const int r = wave * 8 + rr;
    if (sFlag[r]) {
      const int row = rbase + r;
      const float* rrow = src + (size_t)row * DIM;
      float d[4] = {0.f, 0.f, 0.f, 0.f};
      for (int kb = 0; kb < 64; ++kb) {
        const float4 rv = ((const float4*)rrow)[kb];
#pragma unroll
        for (int j = 0; j < 4; ++j) {
          const float4 cv = ((const float4*)(cb + (size_t)(lane + 64 * j) * DIM))[kb];
          d[j] = fmaf(rv.x, cv.x, d[j]);
          d[j] = fmaf(rv.y, cv.y, d[j]);
          d[j] = fmaf(rv.z, cv.z, d[j]);
          d[j] = fmaf(rv.w, cv.w, d[j]);
        }
      }
      const float rn = rnorm[row];
      float bv = 3.4e38f; int be = 0;
#pragma unroll
      for (int j = 0; j < 4; ++j) {
        const int e = lane + 64 * j;
        const float v = (rn - 2.0f * d[j]) + cbn[e];
        if (v < bv) { bv = v; be = e; }
      }
#pragma unroll
      for (int m = 1; m < 64; m <<= 1) {
        const float vo = __shfl_xor(bv, m, 64);
        const int   eo = __shfl_xor(be, m, 64);
        if (vo < bv || (vo == bv && eo < be)) { bv = vo; be = eo; }
      }
      if (lane == 0) sIdx[r] = be;
    }
  }
  __syncthreads();

  // ---- update phase: 2 rows/wave x 4 passes (packed stores are natural 16B) ----
  const int half = lane >> 5, j = lane & 31;
  float msum = 0.0f;
  for (int i = 0; i < 4; ++i) {
    const int rr = i * 8 + wave * 2 + half;
    const int row = rbase + rr;
    const int e = sIdx[rr];
    const float4* rp = (const float4*)(src + (size_t)row * DIM + j * 8);
    float4 r0 = rp[0], r1 = rp[1];
    const float4* qp = (const float4*)(cb + (size_t)e * DIM + j * 8);
    float4 q0 = qp[0], q1 = qp[1];
    float nr[8] = {r0.x - q0.x, r0.y - q0.y, r0.z - q0.z, r0.w - q0.w,
                   r1.x - q1.x, r1.y - q1.y, r1.z - q1.z, r1.w - q1.w};
    float ss = 0.f;
#pragma unroll
    for (int u = 0; u < 8; ++u) ss += nr[u] * nr[u];
    if (stage == 3) {
      // x_q = x - resid_final (skip the per-stage xq accumulation entirely)
      const float4* xr = (const float4*)(xin + (size_t)row * DIM + j * 8);
      float4 x0 = xr[0], x1 = xr[1];
      float4* xp = (float4*)(xq + (size_t)row * DIM + j * 8);
      xp[0] = (float4){x0.x - nr[0], x0.y - nr[1], x0.z - nr[2], x0.w - nr[3]};
      xp[1] = (float4){x1.x - nr[4], x1.y - nr[5], x1.z - nr[6], x1.w - nr[7]};
    }
#pragma unroll
    for (int m = 1; m < 32; m <<= 1) ss += __shfl_xor(ss, m, 64);
    if (stage < 3) {
      float4* rw = (float4*)(resid + (size_t)row * DIM + j * 8);
      rw[0] = (float4){nr[0], nr[1], nr[2], nr[3]};
      rw[1] = (float4){nr[4], nr[5], nr[6], nr[7]};
      const float sc = rsqrtf(ss + 1e-12f);
      ushort8v h, l, xn;
#pragma unroll
      for (int u = 0; u < 8; ++u) {
        h[u] = f2bf(nr[u]); l[u] = f2bf(nr[u] - bf2f(h[u])); xn[u] = f2bf(nr[u] * sc);
      }
      const size_t c = chunkIdx(row, j) * 8;
      *(ushort8v*)(rHp + c) = h;
      *(ushort8v*)(rLp + c) = l;
      *(ushort8v*)(Xnp + c) = xn;
      if (j == 0) rnorm[row] = ss;
    }
    if (j == 0) {
      idxf[(size_t)row * NQ + stage] = (float)e;
      msum += ss;
    }
  }
  msum += __shfl_xor(msum, 32, 64);
  if (lane == 0) sred[wave] = msum;
  __syncthreads();
  if (tid == 0) atomicAdd(&acc[0], sred[0] + sred[1] + sred[2] + sred[3]);
}

// ---------------- finalize scalar outputs ----------------
__global__ void finalize_kernel(const float* __restrict__ acc, float* __restrict__ out) {
  const int t = threadIdx.x;
  if (t == 0) out[ND] = acc[0] * (1.25f / (4.0f * (float)ND));
  if (t < 4) out[ND + 1 + t] = acc[4 + t] * (1.0f / (float)KP);
}

extern "C" void kernel_launch(void* const* d_in, const int* in_sizes, int n_in,
                              void* d_out, int out_size, void* d_ws, size_t ws_size,
                              hipStream_t stream) {
  const float* x         = (const float*)d_in[0];
  const float* codebooks = (const float*)d_in[1];
  const int*   i1        = (const int*)d_in[2];
  const int*   i2        = (const int*)d_in[3];
  float* out = (float*)d_out;
  float* out_xq   = out;                 // [N, D]
  float* out_idxf = out + ND + 1 + NQ;   // [N, NQ] as float

  char* w = (char*)d_ws;
  float*          resid = (float*)w;          w += (size_t)N_ROWS * DIM * 4;
  unsigned short* Xnp   = (unsigned short*)w; w += (size_t)N_ROWS * DIM * 2;
  unsigned short* rHp   = (unsigned short*)w; w += (size_t)N_ROWS * DIM * 2;
  unsigned short* rLp   = (unsigned short*)w; w += (size_t)N_ROWS * DIM * 2;
  float*          rnorm = (float*)w;          w += (size_t)N_ROWS * 4;
  unsigned short* Qgp   = (unsigned short*)w; w += (size_t)KP * DIM * 2;
  float*          pos   = (float*)w;          w += (size_t)KP * 4;
  float*          ssum  = (float*)w;          w += (size_t)KP * 4;
  float*          cbn   = (float*)w;          w += (size_t)NQ * NE * 4;
  unsigned short* cbHp  = (unsigned short*)w; w += (size_t)NQ * NE * DIM * 2;
  unsigned short* cbLp  = (unsigned short*)w; w += (size_t)NQ * NE * DIM * 2;
  float*          acc   = (float*)w;          w += 32;  // [0]=sumsq, [4..7]=outer sums

  prep0_kernel<<<4096, 256, 0, stream>>>(x, Xnp, rnorm, rHp, rLp);
  cbnorm_kernel<<<256, 256, 0, stream>>>(codebooks, cbn);
  cbsplit_kernel<<<128, 256, 0, stream>>>(codebooks, cbHp, cbLp);
  hipMemsetAsync(acc, 0, 32, stream);
  for (int q = 0; q < NQ; ++q) {
    const float* cb = codebooks + (size_t)q * NE * DIM;
    gather_pos_kernel<<<1024, 256, 0, stream>>>(Xnp, i1, i2, Qgp, pos, ssum);
    sim_lse_kernel<<<dim3(32, 64), 256, 0, stream>>>(Qgp, Xnp, ssum);
    lse_final_kernel<<<16, 256, 0, stream>>>(ssum, pos, acc, q);
    argmin_update_kernel<<<1024, 256, 0, stream>>>(
        x, resid, cb, cbHp + (size_t)q * NE * DIM, cbLp + (size_t)q * NE * DIM,
        cbn + q * NE, rnorm, rHp, rLp, out_xq, out_idxf, acc, Xnp, q);
  }
  finalize_kernel<<<1, 64, 0, stream>>>(acc, out);
}